// Round 4
// baseline (854.469 us; speedup 1.0000x reference)
//
#include <hip/hip_runtime.h>
#include <hip/hip_bf16.h>

// Problem constants
#define B_    512
#define HIST_ 8
#define PRED_ 24
#define CITY_ 184
#define FEAT_ 13
#define HID_  32
#define BC_   (B_*CITY_)   // 94208 = 5888 * 16
#define FLAG_OFF 7168

// ws (float) layout (written by prep_all; rows PERMUTED, see below):
//   [0..4095]      Wh2[p*32+k] : W_hh + a0 (x) W_out   (t>=1 path)
//   [4096..6143]   Wf [p*16+f] : W_x[:,1:14], cols 13..15 zeroed
//   [6144..6271]   bg2[p]      : b_g + a0*b_out        (t>=1)
//   [6272..6399]   a0 [p]      : W_x[:,0]              (t==0)
//   [6400..6527]   bg0[p]      : b_g                   (t==0)
//   [6528..6559]   wout[u]     : unit-indexed (NOT permuted)
//   [6560]         bout
//   [7168]         dtype flag: 0.0f = bf16 inputs, 1.0f = fp32 inputs
//
// Row permutation: original gate-row j = 32*gate + u (gate 0..3 = i,f,g,o,
// unit u 0..31) is stored at p = 16*tt + 4*(u>>3) + (psi&3), where
// psi = u&7, tt = 2*gate + (psi>>2).  Consequence: the 16x16 MFMA D-tile
// at lane (rho=lane&15, q=lane>>4) holds rows 16tt+4q+r = gates
// (gate=tt>>1) of units 8q + 4*(tt&1) + r, seq rho -- i.e. each lane owns
// the complete i/f/g/o set for units {8q..8q+7} of its own sequence, which
// is EXACTLY the B-fragment k-slice (k = 8*(lane>>4)+elem) it must supply
// next step.  h never leaves the lane; no LDS at all.

struct TrueT  { static constexpr bool value = true;  };
struct FalseT { static constexpr bool value = false; };

typedef _Float16 v8hf __attribute__((ext_vector_type(8)));
typedef _Float16 v4hf __attribute__((ext_vector_type(4)));
typedef _Float16 v2hf __attribute__((ext_vector_type(2)));
typedef float    v4f  __attribute__((ext_vector_type(4)));

// __builtin_amdgcn_cvt_pkrtz returns __fp16x2; bit-identical to _Float16x2.
__device__ __forceinline__ v2hf pkrtz(float a, float b) {
    return __builtin_bit_cast(v2hf, __builtin_amdgcn_cvt_pkrtz(a, b));
}

__device__ __forceinline__ float rcp_(float x) { return __builtin_amdgcn_rcpf(x); }
__device__ __forceinline__ float cl20(float x) { return fminf(fmaxf(x, -20.0f), 20.0f); }

// 4 reciprocals from ONE v_rcp: 1/a,1/b,1/c,1/d via rcp(abcd) + 9 muls.
// Inputs must be >= 1 and clamped (product <= (1+e^20)^4 = 5.5e34 < f32 max).
__device__ __forceinline__ void inv4(float a, float b, float c, float d,
                                     float& ia, float& ib, float& ic, float& id)
{
    const float ab = a*b, cd = c*d;
    const float r  = rcp_(ab*cd);
    const float iab = r*cd, icd = r*ab;
    ia = iab*b; ib = iab*a; ic = icd*d; id = icd*c;
}

template<bool F32>
__device__ __forceinline__ float ldin(const void* p, long i) {
    if constexpr (F32) return ((const float*)p)[i];
    else               return __bfloat162float(((const __hip_bfloat16*)p)[i]);
}
template<bool F32>
__device__ __forceinline__ void stout(void* p, long i, float v) {
    if constexpr (F32) ((float*)p)[i] = v;
    else               ((__hip_bfloat16*)p)[i] = __float2bfloat16(v);
}

// MFMA wrappers. K16 legacy builtin guarded: the K32 fallback with zero-padded
// element slots is exactly equivalent (A/B share the (lane,elem)->k labeling).
__device__ __forceinline__ v4f mfma_k32(v8hf a, v8hf b, v4f c) {
    return __builtin_amdgcn_mfma_f32_16x16x32_f16(a, b, c, 0, 0, 0);
}
__device__ __forceinline__ v4f mfma_k16(v4hf a, v4hf b, v4f c) {
#if __has_builtin(__builtin_amdgcn_mfma_f32_16x16x16f16)
    return __builtin_amdgcn_mfma_f32_16x16x16f16(a, b, c, 0, 0, 0);
#else
    v8hf a8; v8hf b8;
    #pragma unroll
    for (int j = 0; j < 4; ++j) { a8[j] = a[j]; b8[j] = b[j]; }
    #pragma unroll
    for (int j = 4; j < 8; ++j) { a8[j] = (_Float16)0.f; b8[j] = (_Float16)0.f; }
    return __builtin_amdgcn_mfma_f32_16x16x32_f16(a8, b8, c, 0, 0, 0);
#endif
}

// ---- prep body (templated on dtype), writes permuted rows ----
template<bool F32>
__device__ __forceinline__ void prep_body(const void* W_in, const void* b_in,
                                          const void* W_out, const void* b_out,
                                          const void* W_ih, const void* W_hh,
                                          const void* b_ih, const void* b_hh,
                                          float* ws, int j)
{
    if (j >= 128) return;
    // original gate-row j -> permuted position p
    const int gate = j >> 5;
    const int u    = j & 31;
    const int qb   = u >> 3;
    const int psi  = u & 7;
    const int tt   = 2*gate + (psi >> 2);
    const int p    = 16*tt + 4*qb + (psi & 3);

    float wx[14];
    #pragma unroll
    for (int c = 0; c < 14; ++c) wx[c] = 0.0f;
    float bg = ldin<F32>(b_ih, j) + ldin<F32>(b_hh, j);
    #pragma unroll
    for (int m = 0; m < 32; ++m) {
        float wihm = ldin<F32>(W_ih, j*32 + m);
        #pragma unroll
        for (int c = 0; c < 14; ++c) wx[c] = fmaf(wihm, ldin<F32>(W_in, m*14 + c), wx[c]);
        bg = fmaf(wihm, ldin<F32>(b_in, m), bg);
    }
    float a0 = wx[0];
    #pragma unroll
    for (int k = 0; k < 32; ++k)
        ws[p*32 + k] = ldin<F32>(W_hh, j*32 + k) + a0 * ldin<F32>(W_out, k);
    #pragma unroll
    for (int f = 0; f < 13; ++f) ws[4096 + p*16 + f] = wx[1 + f];
    #pragma unroll
    for (int f = 13; f < 16; ++f) ws[4096 + p*16 + f] = 0.0f;  // pad (never poison)
    float bo = ldin<F32>(b_out, 0);
    ws[6144 + p] = bg + a0 * bo;
    ws[6272 + p] = a0;
    ws[6400 + p] = bg;
    if (j < 32) ws[6528 + j] = ldin<F32>(W_out, j);   // unit-indexed, unpermuted
    if (j == 0) ws[6560] = bo;
}

// ---- fused detect + prep: one launch ----
__global__ void prep_all(const unsigned short* __restrict__ feat_raw,
                         const void* __restrict__ W_in,  const void* __restrict__ b_in,
                         const void* __restrict__ W_out, const void* __restrict__ b_out,
                         const void* __restrict__ W_ih,  const void* __restrict__ W_hh,
                         const void* __restrict__ b_ih,  const void* __restrict__ b_hh,
                         float* __restrict__ ws)
{
    __shared__ int cnt;
    const int tid = threadIdx.x;   // 0..127
    if (tid == 0) cnt = 0;
    __syncthreads();
    int insane = 0;
    for (int i = tid; i < 4096; i += 128) {
        float v = __uint_as_float(((unsigned int)feat_raw[i]) << 16);
        if (!(fabsf(v) < 1e8f)) insane++;
    }
    if (insane) atomicAdd(&cnt, insane);
    __syncthreads();
    const bool f32 = (cnt > 8);
    if (tid == 0) ws[FLAG_OFF] = f32 ? 1.0f : 0.0f;
    if (f32) prep_body<true >(W_in,b_in,W_out,b_out,W_ih,W_hh,b_ih,b_hh,ws,tid);
    else     prep_body<false>(W_in,b_in,W_out,b_out,W_ih,W_hh,b_ih,b_hh,ws,tid);
}

// ---- main LSTM body: zero LDS, h recirculates in-register ----
template<bool F32>
__device__ __forceinline__ void lstm_body(const void* __restrict__ pm25,
                                          const void* __restrict__ feat,
                                          const float* __restrict__ ws,
                                          void* __restrict__ out)
{
    const int lane = threadIdx.x & 63;
    const int rho  = lane & 15;      // seq within wave / A-row / D-col
    const int q    = lane >> 4;      // k-block / D-row-block / unit-block
    const int wseq = blockIdx.x * 16;
    const int seq  = wseq + rho;
    const int bb   = seq / CITY_;
    const int city = seq - bb*CITY_;

    // ---- weights -> fp16 hi/lo A-fragments (once per wave) ----
    v8hf Whi0[8], Wlo0[8];
    v4hf Whi1[8], Wlo1[8];
    v4f  bias2[8];
    #pragma unroll
    for (int tt = 0; tt < 8; ++tt) {
        const float* wr = ws + (16*tt + rho)*32 + 8*q;
        #pragma unroll
        for (int j = 0; j < 8; ++j) {
            const float w = wr[j];
            const _Float16 h = (_Float16)w;
            Whi0[tt][j] = h;
            Wlo0[tt][j] = (_Float16)(w - (float)h);
        }
        const float* wf = ws + 4096 + (16*tt + rho)*16 + 4*q;
        #pragma unroll
        for (int j = 0; j < 4; ++j) {
            const float w = wf[j];
            const _Float16 h = (_Float16)w;
            Whi1[tt][j] = h;
            Wlo1[tt][j] = (_Float16)(w - (float)h);
        }
        bias2[tt] = *(const v4f*)(ws + 6144 + 16*tt + 4*q);   // C rows 16tt+4q+r
    }
    float wo8[8];
    #pragma unroll
    for (int j = 0; j < 8; ++j) wo8[j] = ws[6528 + 8*q + j]; // wout[unit 8q+j]
    const float bo = ws[6560];
    const long obase = (long)bb*PRED_*CITY_ + city;

    // ---- per-lane direct feature loads (no LDS): elems 4q..4q+3, clamped.
    // Cols 13..15 of Wf are exactly zero, so clamped duplicates contribute 0.
    int eoff[4];
    #pragma unroll
    for (int j = 0; j < 4; ++j) {
        const int e = 4*q + j;
        eoff[j] = (e < FEAT_) ? e : (FEAT_-1);
    }
    long fbase = ((long)(bb*(HIST_+PRED_) + HIST_)*CITY_ + city)*FEAT_;
    float fn[4];
    auto ldfeat = [&]() {            // prefetch one step's 4 elems into regs
        #pragma unroll
        for (int j = 0; j < 4; ++j) fn[j] = ldin<F32>(feat, fbase + eoff[j]);
        fbase += CITY_ * FEAT_;
    };
    v4hf fhi, flo;
    auto convf = [&]() {             // fn (step t raw) -> fp16 hi/lo fragment
        #pragma unroll
        for (int jj = 0; jj < 2; ++jj) {
            const v2hf ph = pkrtz(fn[2*jj], fn[2*jj+1]);
            fhi[2*jj] = ph[0]; fhi[2*jj+1] = ph[1];
            if constexpr (F32) {
                const v2hf pl = pkrtz(fn[2*jj] - (float)ph[0],
                                      fn[2*jj+1] - (float)ph[1]);
                flo[2*jj] = pl[0]; flo[2*jj+1] = pl[1];
            }
        }
    };

    float cst[8];                    // c-state, units 8q+psi, seq rho
    v8hf  xhi, xlo;                  // h hi/lo: next step's B chunk0 (in-lane!)

    // finish: cell nonlinearity, trans-minimized.
    // sigma(x) = 1/(e^-x + 1); tanh(x) = 1 - 2/(e^{2x}+1); all via quad-rcp.
    // Clamp +-20 (sigma/tanh err <= 2e-9) prevents inf poisoning quad partners.
    auto finishT = [&](v4f (&acc)[8], int t, auto T0flag) {
        constexpr bool T0 = decltype(T0flag)::value;
        float h[8];
        float y = 0.0f;
        #pragma unroll
        for (int hf = 0; hf < 2; ++hf) {   // psi = 4*hf + r; tiles tl = hf
            float di[4], df[4], dg[4], dq[4];
            #pragma unroll
            for (int r = 0; r < 4; ++r) {
                di[r] = 1.0f + __expf(-cl20(acc[hf    ][r]));
                df[r] = 1.0f + __expf(-cl20(acc[2 + hf][r]));
                dg[r] = 1.0f + __expf( cl20(acc[4 + hf][r] * 2.0f));
                dq[r] = 1.0f + __expf(-cl20(acc[6 + hf][r]));
            }
            float I[4], F[4], Gi[4], O[4];
            inv4(di[0],di[1],di[2],di[3], I[0],I[1],I[2],I[3]);
            inv4(df[0],df[1],df[2],df[3], F[0],F[1],F[2],F[3]);
            inv4(dg[0],dg[1],dg[2],dg[3], Gi[0],Gi[1],Gi[2],Gi[3]);
            inv4(dq[0],dq[1],dq[2],dq[3], O[0],O[1],O[2],O[3]);
            float dc[4];
            #pragma unroll
            for (int r = 0; r < 4; ++r) {
                const float G  = 1.0f - 2.0f*Gi[r];
                const float ig = I[r]*G;
                float c;
                if constexpr (T0) c = ig;
                else              c = fmaf(F[r], cst[4*hf + r], ig);
                cst[4*hf + r] = c;
                dc[r] = 1.0f + __expf(cl20(c * 2.0f));
            }
            float Tc[4];
            inv4(dc[0],dc[1],dc[2],dc[3], Tc[0],Tc[1],Tc[2],Tc[3]);
            #pragma unroll
            for (int r = 0; r < 4; ++r) {
                const float hv = O[r] * (1.0f - 2.0f*Tc[r]);
                h[4*hf + r] = hv;
                y = fmaf(wo8[4*hf + r], hv, y);
            }
        }
        #pragma unroll
        for (int jj = 0; jj < 4; ++jj) {   // pack -> next B fragment (RTZ hi,
            const v2hf ph = pkrtz(h[2*jj], h[2*jj+1]);
            xhi[2*jj] = ph[0]; xhi[2*jj+1] = ph[1];   // lo exactly compensates)
            const v2hf pl = pkrtz(h[2*jj] - (float)ph[0],
                                  h[2*jj+1] - (float)ph[1]);
            xlo[2*jj] = pl[0]; xlo[2*jj+1] = pl[1];
        }
        y += __shfl_xor(y, 16);
        y += __shfl_xor(y, 32);
        if (q == 0) stout<F32>(out, obase + (long)t*CITY_, y + bo);
    };

    // ---- t = 0 : gates = a0*x0 + bg0 (C-init) + Wf.feat (h0 = 0) ----
    ldfeat();            // t=0 features
    convf();
    ldfeat();            // t=1 features in flight
    {
        const float x0 = ldin<F32>(pm25, (long)(bb*HIST_ + (HIST_-1))*CITY_ + city);
        v4f acc[8];
        __builtin_amdgcn_s_setprio(1);
        #pragma unroll
        for (int tt = 0; tt < 8; ++tt) {
            const v4f bg0 = *(const v4f*)(ws + 6400 + 16*tt + 4*q);
            const v4f a0  = *(const v4f*)(ws + 6272 + 16*tt + 4*q);
            v4f c;
            #pragma unroll
            for (int r = 0; r < 4; ++r) c[r] = fmaf(a0[r], x0, bg0[r]);
            v4f a = mfma_k16(Whi1[tt], fhi, c);
            a = mfma_k16(Wlo1[tt], fhi, a);
            if constexpr (F32) a = mfma_k16(Whi1[tt], flo, a);
            acc[tt] = a;
        }
        __builtin_amdgcn_s_setprio(0);
        finishT(acc, 0, TrueT{});
    }

    // ---- t = 1..23 ----
    #pragma unroll 1
    for (int t = 1; t < PRED_; ++t) {
        convf();                        // features for t (loaded last iter)
        if (t < PRED_-1) ldfeat();      // prefetch t+1
        v4f acc[8];
        __builtin_amdgcn_s_setprio(1);
        #pragma unroll
        for (int tt = 0; tt < 8; ++tt) {
            v4f a = mfma_k32(Whi0[tt], xhi, bias2[tt]);
            a = mfma_k32(Wlo0[tt], xhi, a);
            a = mfma_k32(Whi0[tt], xlo, a);
            a = mfma_k16(Whi1[tt], fhi, a);
            a = mfma_k16(Wlo1[tt], fhi, a);
            if constexpr (F32) a = mfma_k16(Whi1[tt], flo, a);
            acc[tt] = a;
        }
        __builtin_amdgcn_s_setprio(0);
        finishT(acc, t, FalseT{});
    }
}

__global__ __launch_bounds__(64, 4) void lstm_main(
    const void* __restrict__ pm25,   // (512, 8, 184, 1)
    const void* __restrict__ feat,   // (512, 32, 184, 13)
    const float* __restrict__ ws,
    void* __restrict__ out)          // (512, 24, 184, 1)
{
    const bool f32 = (ws[FLAG_OFF] == 1.0f);   // wave-uniform runtime branch
    if (f32) lstm_body<true >(pm25, feat, ws, out);
    else     lstm_body<false>(pm25, feat, ws, out);
}

extern "C" void kernel_launch(void* const* d_in, const int* in_sizes, int n_in,
                              void* d_out, int out_size, void* d_ws, size_t ws_size,
                              hipStream_t stream) {
    const void* pm25  = d_in[0];
    const void* feat  = d_in[1];
    const void* W_in  = d_in[2];
    const void* b_in  = d_in[3];
    const void* W_out = d_in[4];
    const void* b_out = d_in[5];
    const void* W_ih  = d_in[6];
    const void* W_hh  = d_in[7];
    const void* b_ih  = d_in[8];
    const void* b_hh  = d_in[9];
    float* ws = (float*)d_ws;

    prep_all<<<dim3(1), dim3(128), 0, stream>>>(
        (const unsigned short*)feat, W_in, b_in, W_out, b_out,
        W_ih, W_hh, b_ih, b_hh, ws);

    lstm_main<<<dim3(BC_/16), dim3(64), 0, stream>>>(pm25, feat, ws, d_out);
}

// Round 6
// 368.865 us; speedup vs baseline: 2.3165x; 2.3165x over previous
//
#include <hip/hip_runtime.h>
#include <hip/hip_bf16.h>

// Problem constants
#define B_    512
#define HIST_ 8
#define PRED_ 24
#define CITY_ 184
#define FEAT_ 13
#define HID_  32
#define BC_   (B_*CITY_)   // 94208 = 1472 * 64
#define FLAG_OFF 7168

// ws (float) layout (written by prep_all; rows PERMUTED, see below):
//   [0..4095]      Wh2[p*32+k] : W_hh + a0 (x) W_out   (t>=1 path)
//   [4096..6143]   Wf [p*16+f] : W_x[:,1:14], cols 13..15 zeroed
//   [6144..6271]   bg2[p]      : b_g + a0*b_out        (t>=1)
//   [6272..6399]   a0 [p]      : W_x[:,0]              (t==0)
//   [6400..6527]   bg0[p]      : b_g                   (t==0)
//   [6528..6559]   wout[u]     : unit-indexed (NOT permuted)
//   [6560]         bout
//   [7168]         dtype flag: 0.0f = bf16 inputs, 1.0f = fp32 inputs
//
// Row permutation: original gate-row j = 32*gate + u (gate 0..3 = i,f,g,o,
// unit u 0..31) is stored at p = 16*tt + 4*(u>>3) + (psi&3), where
// psi = u&7, tt = 2*gate + (psi>>2).  The 16x16 MFMA D-tile at lane
// (rho=lane&15, q=lane>>4) then holds the complete i/f/g/o set for units
// {8q..8q+7} of seq rho == exactly the B-fragment k-slice (k=8q+elem) the
// lane must supply next step.  h never leaves the lane; no LDS at all.
//
// NOTE (R4 post-mortem): register working set is ~190 VGPRs.  launch_bounds
// (64,4) capped the allocator at 128 -> 64-VGPR spill-fest (FETCH 60MB ->
// 1.3GB scratch traffic, 4x slower).  Keep (256,2): cap 256.
// NOTE (R5 post-mortem): s_setprio(1/0) bracketing the MFMA cluster in the
// clean (non-spill) build corrupted results (absmax 1.8e-2 + unwritten
// outputs); value-math (quad-rcp, pkrtz) is geometry-independent and cannot
// explain pass@R4/fail@R5.  setprio REMOVED -- do not reintroduce.

struct TrueT  { static constexpr bool value = true;  };
struct FalseT { static constexpr bool value = false; };

typedef _Float16 v8hf __attribute__((ext_vector_type(8)));
typedef _Float16 v4hf __attribute__((ext_vector_type(4)));
typedef _Float16 v2hf __attribute__((ext_vector_type(2)));
typedef float    v4f  __attribute__((ext_vector_type(4)));

// __builtin_amdgcn_cvt_pkrtz returns __fp16x2; bit-identical to _Float16x2.
__device__ __forceinline__ v2hf pkrtz(float a, float b) {
    return __builtin_bit_cast(v2hf, __builtin_amdgcn_cvt_pkrtz(a, b));
}

__device__ __forceinline__ float rcp_(float x) { return __builtin_amdgcn_rcpf(x); }
__device__ __forceinline__ float cl20(float x) { return fminf(fmaxf(x, -20.0f), 20.0f); }

// 4 reciprocals from ONE v_rcp: 1/a,1/b,1/c,1/d via rcp(abcd) + 9 muls.
// Inputs must be >= 1 and clamped (product <= (1+e^20)^4 = 5.5e34 < f32 max).
__device__ __forceinline__ void inv4(float a, float b, float c, float d,
                                     float& ia, float& ib, float& ic, float& id)
{
    const float ab = a*b, cd = c*d;
    const float r  = rcp_(ab*cd);
    const float iab = r*cd, icd = r*ab;
    ia = iab*b; ib = iab*a; ic = icd*d; id = icd*c;
}

template<bool F32>
__device__ __forceinline__ float ldin(const void* p, long i) {
    if constexpr (F32) return ((const float*)p)[i];
    else               return __bfloat162float(((const __hip_bfloat16*)p)[i]);
}
template<bool F32>
__device__ __forceinline__ void stout(void* p, long i, float v) {
    if constexpr (F32) ((float*)p)[i] = v;
    else               ((__hip_bfloat16*)p)[i] = __float2bfloat16(v);
}

// MFMA wrappers. K16 legacy builtin guarded: the K32 fallback with zero-padded
// element slots is exactly equivalent (A/B share the (lane,elem)->k labeling).
__device__ __forceinline__ v4f mfma_k32(v8hf a, v8hf b, v4f c) {
    return __builtin_amdgcn_mfma_f32_16x16x32_f16(a, b, c, 0, 0, 0);
}
__device__ __forceinline__ v4f mfma_k16(v4hf a, v4hf b, v4f c) {
#if __has_builtin(__builtin_amdgcn_mfma_f32_16x16x16f16)
    return __builtin_amdgcn_mfma_f32_16x16x16f16(a, b, c, 0, 0, 0);
#else
    v8hf a8; v8hf b8;
    #pragma unroll
    for (int j = 0; j < 4; ++j) { a8[j] = a[j]; b8[j] = b[j]; }
    #pragma unroll
    for (int j = 4; j < 8; ++j) { a8[j] = (_Float16)0.f; b8[j] = (_Float16)0.f; }
    return __builtin_amdgcn_mfma_f32_16x16x32_f16(a8, b8, c, 0, 0, 0);
#endif
}

// ---- prep body (templated on dtype), writes permuted rows ----
template<bool F32>
__device__ __forceinline__ void prep_body(const void* W_in, const void* b_in,
                                          const void* W_out, const void* b_out,
                                          const void* W_ih, const void* W_hh,
                                          const void* b_ih, const void* b_hh,
                                          float* ws, int j)
{
    if (j >= 128) return;
    // original gate-row j -> permuted position p
    const int gate = j >> 5;
    const int u    = j & 31;
    const int qb   = u >> 3;
    const int psi  = u & 7;
    const int tt   = 2*gate + (psi >> 2);
    const int p    = 16*tt + 4*qb + (psi & 3);

    float wx[14];
    #pragma unroll
    for (int c = 0; c < 14; ++c) wx[c] = 0.0f;
    float bg = ldin<F32>(b_ih, j) + ldin<F32>(b_hh, j);
    #pragma unroll
    for (int m = 0; m < 32; ++m) {
        float wihm = ldin<F32>(W_ih, j*32 + m);
        #pragma unroll
        for (int c = 0; c < 14; ++c) wx[c] = fmaf(wihm, ldin<F32>(W_in, m*14 + c), wx[c]);
        bg = fmaf(wihm, ldin<F32>(b_in, m), bg);
    }
    float a0 = wx[0];
    #pragma unroll
    for (int k = 0; k < 32; ++k)
        ws[p*32 + k] = ldin<F32>(W_hh, j*32 + k) + a0 * ldin<F32>(W_out, k);
    #pragma unroll
    for (int f = 0; f < 13; ++f) ws[4096 + p*16 + f] = wx[1 + f];
    #pragma unroll
    for (int f = 13; f < 16; ++f) ws[4096 + p*16 + f] = 0.0f;  // pad (never poison)
    float bo = ldin<F32>(b_out, 0);
    ws[6144 + p] = bg + a0 * bo;
    ws[6272 + p] = a0;
    ws[6400 + p] = bg;
    if (j < 32) ws[6528 + j] = ldin<F32>(W_out, j);   // unit-indexed, unpermuted
    if (j == 0) ws[6560] = bo;
}

// ---- fused detect + prep: one launch ----
__global__ void prep_all(const unsigned short* __restrict__ feat_raw,
                         const void* __restrict__ W_in,  const void* __restrict__ b_in,
                         const void* __restrict__ W_out, const void* __restrict__ b_out,
                         const void* __restrict__ W_ih,  const void* __restrict__ W_hh,
                         const void* __restrict__ b_ih,  const void* __restrict__ b_hh,
                         float* __restrict__ ws)
{
    __shared__ int cnt;
    const int tid = threadIdx.x;   // 0..127
    if (tid == 0) cnt = 0;
    __syncthreads();
    int insane = 0;
    for (int i = tid; i < 4096; i += 128) {
        float v = __uint_as_float(((unsigned int)feat_raw[i]) << 16);
        if (!(fabsf(v) < 1e8f)) insane++;
    }
    if (insane) atomicAdd(&cnt, insane);
    __syncthreads();
    const bool f32 = (cnt > 8);
    if (tid == 0) ws[FLAG_OFF] = f32 ? 1.0f : 0.0f;
    if (f32) prep_body<true >(W_in,b_in,W_out,b_out,W_ih,W_hh,b_ih,b_hh,ws,tid);
    else     prep_body<false>(W_in,b_in,W_out,b_out,W_ih,W_hh,b_ih,b_hh,ws,tid);
}

// ---- main LSTM body: zero LDS, h recirculates in-register ----
template<bool F32>
__device__ __forceinline__ void lstm_body(const void* __restrict__ pm25,
                                          const void* __restrict__ feat,
                                          const float* __restrict__ ws,
                                          void* __restrict__ out)
{
    const int lane = threadIdx.x & 63;
    const int rho  = lane & 15;      // seq within wave / A-row / D-col
    const int q    = lane >> 4;      // k-block / D-row-block / unit-block
    const int wv   = threadIdx.x >> 6;
    const int wseq = (blockIdx.x*4 + wv) * 16;
    const int seq  = wseq + rho;
    const int bb   = seq / CITY_;
    const int city = seq - bb*CITY_;

    // ---- weights -> fp16 hi/lo A-fragments (once per wave) ----
    v8hf Whi0[8], Wlo0[8];
    v4hf Whi1[8], Wlo1[8];
    v4f  bias2[8];
    #pragma unroll
    for (int tt = 0; tt < 8; ++tt) {
        const float* wr = ws + (16*tt + rho)*32 + 8*q;
        #pragma unroll
        for (int j = 0; j < 8; ++j) {
            const float w = wr[j];
            const _Float16 h = (_Float16)w;
            Whi0[tt][j] = h;
            Wlo0[tt][j] = (_Float16)(w - (float)h);
        }
        const float* wf = ws + 4096 + (16*tt + rho)*16 + 4*q;
        #pragma unroll
        for (int j = 0; j < 4; ++j) {
            const float w = wf[j];
            const _Float16 h = (_Float16)w;
            Whi1[tt][j] = h;
            Wlo1[tt][j] = (_Float16)(w - (float)h);
        }
        bias2[tt] = *(const v4f*)(ws + 6144 + 16*tt + 4*q);   // C rows 16tt+4q+r
    }
    float wo8[8];
    #pragma unroll
    for (int j = 0; j < 8; ++j) wo8[j] = ws[6528 + 8*q + j]; // wout[unit 8q+j]
    const float bo = ws[6560];
    const long obase = (long)bb*PRED_*CITY_ + city;

    // ---- per-lane direct feature loads (no LDS): elems 4q..4q+3, clamped.
    // Cols 13..15 of Wf are exactly zero, so clamped duplicates contribute 0.
    int eoff[4];
    #pragma unroll
    for (int j = 0; j < 4; ++j) {
        const int e = 4*q + j;
        eoff[j] = (e < FEAT_) ? e : (FEAT_-1);
    }
    long fbase = ((long)(bb*(HIST_+PRED_) + HIST_)*CITY_ + city)*FEAT_;
    float fn[4];
    auto ldfeat = [&]() {            // prefetch one step's 4 elems into regs
        #pragma unroll
        for (int j = 0; j < 4; ++j) fn[j] = ldin<F32>(feat, fbase + eoff[j]);
        fbase += CITY_ * FEAT_;
    };
    v4hf fhi, flo;
    auto convf = [&]() {             // fn (step t raw) -> fp16 hi/lo fragment
        #pragma unroll
        for (int jj = 0; jj < 2; ++jj) {
            const v2hf ph = pkrtz(fn[2*jj], fn[2*jj+1]);
            fhi[2*jj] = ph[0]; fhi[2*jj+1] = ph[1];
            if constexpr (F32) {
                const v2hf pl = pkrtz(fn[2*jj] - (float)ph[0],
                                      fn[2*jj+1] - (float)ph[1]);
                flo[2*jj] = pl[0]; flo[2*jj+1] = pl[1];
            }
        }
    };

    float cst[8];                    // c-state, units 8q+psi, seq rho
    v8hf  xhi, xlo;                  // h hi/lo: next step's B chunk0 (in-lane!)

    // finish: cell nonlinearity, trans-minimized.
    // sigma(x) = 1/(e^-x + 1); tanh(x) = 1 - 2/(e^{2x}+1); all via quad-rcp.
    // Clamp +-20 (sigma/tanh err <= 2e-9) prevents inf poisoning quad partners.
    auto finishT = [&](v4f (&acc)[8], int t, auto T0flag) {
        constexpr bool T0 = decltype(T0flag)::value;
        float h[8];
        float y = 0.0f;
        #pragma unroll
        for (int hf = 0; hf < 2; ++hf) {   // psi = 4*hf + r; tiles tl = hf
            float di[4], df[4], dg[4], dq[4];
            #pragma unroll
            for (int r = 0; r < 4; ++r) {
                di[r] = 1.0f + __expf(-cl20(acc[hf    ][r]));
                df[r] = 1.0f + __expf(-cl20(acc[2 + hf][r]));
                dg[r] = 1.0f + __expf( cl20(acc[4 + hf][r] * 2.0f));
                dq[r] = 1.0f + __expf(-cl20(acc[6 + hf][r]));
            }
            float I[4], F[4], Gi[4], O[4];
            inv4(di[0],di[1],di[2],di[3], I[0],I[1],I[2],I[3]);
            inv4(df[0],df[1],df[2],df[3], F[0],F[1],F[2],F[3]);
            inv4(dg[0],dg[1],dg[2],dg[3], Gi[0],Gi[1],Gi[2],Gi[3]);
            inv4(dq[0],dq[1],dq[2],dq[3], O[0],O[1],O[2],O[3]);
            float dc[4];
            #pragma unroll
            for (int r = 0; r < 4; ++r) {
                const float G  = 1.0f - 2.0f*Gi[r];
                const float ig = I[r]*G;
                float c;
                if constexpr (T0) c = ig;
                else              c = fmaf(F[r], cst[4*hf + r], ig);
                cst[4*hf + r] = c;
                dc[r] = 1.0f + __expf(cl20(c * 2.0f));
            }
            float Tc[4];
            inv4(dc[0],dc[1],dc[2],dc[3], Tc[0],Tc[1],Tc[2],Tc[3]);
            #pragma unroll
            for (int r = 0; r < 4; ++r) {
                const float hv = O[r] * (1.0f - 2.0f*Tc[r]);
                h[4*hf + r] = hv;
                y = fmaf(wo8[4*hf + r], hv, y);
            }
        }
        #pragma unroll
        for (int jj = 0; jj < 4; ++jj) {   // pack -> next B fragment (RTZ hi,
            const v2hf ph = pkrtz(h[2*jj], h[2*jj+1]);
            xhi[2*jj] = ph[0]; xhi[2*jj+1] = ph[1];   // lo exactly compensates)
            const v2hf pl = pkrtz(h[2*jj] - (float)ph[0],
                                  h[2*jj+1] - (float)ph[1]);
            xlo[2*jj] = pl[0]; xlo[2*jj+1] = pl[1];
        }
        y += __shfl_xor(y, 16);
        y += __shfl_xor(y, 32);
        if (q == 0) stout<F32>(out, obase + (long)t*CITY_, y + bo);
    };

    // ---- t = 0 : gates = a0*x0 + bg0 (C-init) + Wf.feat (h0 = 0) ----
    ldfeat();            // t=0 features
    convf();
    ldfeat();            // t=1 features in flight
    {
        const float x0 = ldin<F32>(pm25, (long)(bb*HIST_ + (HIST_-1))*CITY_ + city);
        v4f acc[8];
        #pragma unroll
        for (int tt = 0; tt < 8; ++tt) {
            const v4f bg0 = *(const v4f*)(ws + 6400 + 16*tt + 4*q);
            const v4f a0  = *(const v4f*)(ws + 6272 + 16*tt + 4*q);
            v4f c;
            #pragma unroll
            for (int r = 0; r < 4; ++r) c[r] = fmaf(a0[r], x0, bg0[r]);
            v4f a = mfma_k16(Whi1[tt], fhi, c);
            a = mfma_k16(Wlo1[tt], fhi, a);
            if constexpr (F32) a = mfma_k16(Whi1[tt], flo, a);
            acc[tt] = a;
        }
        finishT(acc, 0, TrueT{});
    }

    // ---- t = 1..23 ----
    #pragma unroll 1
    for (int t = 1; t < PRED_; ++t) {
        convf();                        // features for t (loaded last iter)
        if (t < PRED_-1) ldfeat();      // prefetch t+1
        v4f acc[8];
        #pragma unroll
        for (int tt = 0; tt < 8; ++tt) {
            v4f a = mfma_k32(Whi0[tt], xhi, bias2[tt]);
            a = mfma_k32(Wlo0[tt], xhi, a);
            a = mfma_k32(Whi0[tt], xlo, a);
            a = mfma_k16(Whi1[tt], fhi, a);
            a = mfma_k16(Wlo1[tt], fhi, a);
            if constexpr (F32) a = mfma_k16(Whi1[tt], flo, a);
            acc[tt] = a;
        }
        finishT(acc, t, FalseT{});
    }
}

__global__ __launch_bounds__(256, 2) void lstm_main(
    const void* __restrict__ pm25,   // (512, 8, 184, 1)
    const void* __restrict__ feat,   // (512, 32, 184, 13)
    const float* __restrict__ ws,
    void* __restrict__ out)          // (512, 24, 184, 1)
{
    const bool f32 = (ws[FLAG_OFF] == 1.0f);   // wave-uniform runtime branch
    if (f32) lstm_body<true >(pm25, feat, ws, out);
    else     lstm_body<false>(pm25, feat, ws, out);
}

extern "C" void kernel_launch(void* const* d_in, const int* in_sizes, int n_in,
                              void* d_out, int out_size, void* d_ws, size_t ws_size,
                              hipStream_t stream) {
    const void* pm25  = d_in[0];
    const void* feat  = d_in[1];
    const void* W_in  = d_in[2];
    const void* b_in  = d_in[3];
    const void* W_out = d_in[4];
    const void* b_out = d_in[5];
    const void* W_ih  = d_in[6];
    const void* W_hh  = d_in[7];
    const void* b_ih  = d_in[8];
    const void* b_hh  = d_in[9];
    float* ws = (float*)d_ws;

    prep_all<<<dim3(1), dim3(128), 0, stream>>>(
        (const unsigned short*)feat, W_in, b_in, W_out, b_out,
        W_ih, W_hh, b_ih, b_hh, ws);

    lstm_main<<<dim3(BC_/64), dim3(256), 0, stream>>>(pm25, feat, ws, d_out);
}

// Round 7
// 346.028 us; speedup vs baseline: 2.4694x; 1.0660x over previous
//
#include <hip/hip_runtime.h>
#include <hip/hip_bf16.h>

// Problem constants
#define B_    512
#define HIST_ 8
#define PRED_ 24
#define CITY_ 184
#define FEAT_ 13
#define HID_  32
#define BC_   (B_*CITY_)   // 94208 = 1472 * 64
#define FLAG_OFF 7168

// ws (float) layout (written by prep_all; rows PERMUTED, see below):
//   [0..4095]      Wh2[p*32+k] : W_hh + a0 (x) W_out   (t>=1 path)
//   [4096..6143]   Wf [p*16+f] : f<13: W_x[:,1+f]; f==13: bg2 (bias column,
//                                feature elem 13 is constant 1.0); f=14,15: 0
//   [6144..6271]   (legacy bg2[p], unused)
//   [6272..6399]   a0 [p]      : W_x[:,0]              (t==0)
//   [6400..6527]   (legacy bg0[p], unused)
//   [6528..6559]   wout[u]     : unit-indexed (NOT permuted)
//   [6560]         bout
//   [7168]         dtype flag: 0.0f = bf16 inputs, 1.0f = fp32 inputs
//
// Row permutation: original gate-row j = 32*gate + u (gate 0..3 = i,f,g,o,
// unit u 0..31) is stored at p = 16*tt + 4*(u>>3) + (psi&3), where
// psi = u&7, tt = 2*gate + (psi>>2).  The 16x16 MFMA D-tile at lane
// (rho=lane&15, q=lane>>4) then holds the complete i/f/g/o set for units
// {8q..8q+7} of seq rho == exactly the B-fragment k-slice (k=8q+elem) the
// lane must supply next step.  h never leaves the lane; no LDS at all.
//
// NOTE (R4): working set needs VGPR cap >= ~170; capping at 128 caused a
// 64-VGPR spill-fest (FETCH 60MB -> 1.3GB scratch).  bf16 kernel is lean
// (~130 regs) -> (256,3) cap 170 safe.  fp32 kernel keeps (256,2).
// NOTE (R5): s_setprio corrupted results in the clean build.  Never again.
// NOTE (R6): quad-rcp/inv4 + clamps REGRESSED (V rose: longer dep chains,
// +170 VALU ops vs -30 rcp).  Trans ops are 16 cyc; plain sigf/tanhf_ wins.

struct TrueT  { static constexpr bool value = true;  };
struct FalseT { static constexpr bool value = false; };

typedef _Float16 v8hf __attribute__((ext_vector_type(8)));
typedef _Float16 v4hf __attribute__((ext_vector_type(4)));
typedef _Float16 v2hf __attribute__((ext_vector_type(2)));
typedef float    v4f  __attribute__((ext_vector_type(4)));

// __builtin_amdgcn_cvt_pkrtz returns __fp16x2; bit-identical to _Float16x2.
__device__ __forceinline__ v2hf pkrtz(float a, float b) {
    return __builtin_bit_cast(v2hf, __builtin_amdgcn_cvt_pkrtz(a, b));
}

__device__ __forceinline__ float rcp_(float x) { return __builtin_amdgcn_rcpf(x); }
__device__ __forceinline__ float sigf(float x) { return rcp_(1.0f + __expf(-x)); }
__device__ __forceinline__ float tanhf_(float x) {
    float e = __expf(2.0f * x);
    return 1.0f - 2.0f * rcp_(e + 1.0f);   // saturates correctly (rcp(inf)=0)
}

template<bool F32>
__device__ __forceinline__ float ldin(const void* p, long i) {
    if constexpr (F32) return ((const float*)p)[i];
    else               return __bfloat162float(((const __hip_bfloat16*)p)[i]);
}
template<bool F32>
__device__ __forceinline__ void stout(void* p, long i, float v) {
    if constexpr (F32) ((float*)p)[i] = v;
    else               ((__hip_bfloat16*)p)[i] = __float2bfloat16(v);
}

// MFMA wrappers. K16 legacy builtin guarded: the K32 fallback with zero-padded
// element slots is exactly equivalent (A/B share the (lane,elem)->k labeling).
__device__ __forceinline__ v4f mfma_k32(v8hf a, v8hf b, v4f c) {
    return __builtin_amdgcn_mfma_f32_16x16x32_f16(a, b, c, 0, 0, 0);
}
__device__ __forceinline__ v4f mfma_k16(v4hf a, v4hf b, v4f c) {
#if __has_builtin(__builtin_amdgcn_mfma_f32_16x16x16f16)
    return __builtin_amdgcn_mfma_f32_16x16x16f16(a, b, c, 0, 0, 0);
#else
    v8hf a8; v8hf b8;
    #pragma unroll
    for (int j = 0; j < 4; ++j) { a8[j] = a[j]; b8[j] = b[j]; }
    #pragma unroll
    for (int j = 4; j < 8; ++j) { a8[j] = (_Float16)0.f; b8[j] = (_Float16)0.f; }
    return __builtin_amdgcn_mfma_f32_16x16x32_f16(a8, b8, c, 0, 0, 0);
#endif
}

// ---- prep body (templated on dtype), writes permuted rows ----
template<bool F32>
__device__ __forceinline__ void prep_body(const void* W_in, const void* b_in,
                                          const void* W_out, const void* b_out,
                                          const void* W_ih, const void* W_hh,
                                          const void* b_ih, const void* b_hh,
                                          float* ws, int j)
{
    if (j >= 128) return;
    // original gate-row j -> permuted position p
    const int gate = j >> 5;
    const int u    = j & 31;
    const int qb   = u >> 3;
    const int psi  = u & 7;
    const int tt   = 2*gate + (psi >> 2);
    const int p    = 16*tt + 4*qb + (psi & 3);

    float wx[14];
    #pragma unroll
    for (int c = 0; c < 14; ++c) wx[c] = 0.0f;
    float bg = ldin<F32>(b_ih, j) + ldin<F32>(b_hh, j);
    #pragma unroll
    for (int m = 0; m < 32; ++m) {
        float wihm = ldin<F32>(W_ih, j*32 + m);
        #pragma unroll
        for (int c = 0; c < 14; ++c) wx[c] = fmaf(wihm, ldin<F32>(W_in, m*14 + c), wx[c]);
        bg = fmaf(wihm, ldin<F32>(b_in, m), bg);
    }
    float a0 = wx[0];
    #pragma unroll
    for (int k = 0; k < 32; ++k)
        ws[p*32 + k] = ldin<F32>(W_hh, j*32 + k) + a0 * ldin<F32>(W_out, k);
    #pragma unroll
    for (int f = 0; f < 13; ++f) ws[4096 + p*16 + f] = wx[1 + f];
    float bo = ldin<F32>(b_out, 0);
    const float bg2 = bg + a0 * bo;
    ws[4096 + p*16 + 13] = bg2;    // bias column: feature elem 13 loads 1.0
    ws[4096 + p*16 + 14] = 0.0f;   // pad (never poison)
    ws[4096 + p*16 + 15] = 0.0f;
    ws[6144 + p] = bg2;            // legacy (unused)
    ws[6272 + p] = a0;
    ws[6400 + p] = bg;             // legacy (unused)
    if (j < 32) ws[6528 + j] = ldin<F32>(W_out, j);   // unit-indexed, unpermuted
    if (j == 0) ws[6560] = bo;
}

// ---- fused detect + prep: one launch ----
__global__ void prep_all(const unsigned short* __restrict__ feat_raw,
                         const void* __restrict__ W_in,  const void* __restrict__ b_in,
                         const void* __restrict__ W_out, const void* __restrict__ b_out,
                         const void* __restrict__ W_ih,  const void* __restrict__ W_hh,
                         const void* __restrict__ b_ih,  const void* __restrict__ b_hh,
                         float* __restrict__ ws)
{
    __shared__ int cnt;
    const int tid = threadIdx.x;   // 0..127
    if (tid == 0) cnt = 0;
    __syncthreads();
    int insane = 0;
    for (int i = tid; i < 4096; i += 128) {
        float v = __uint_as_float(((unsigned int)feat_raw[i]) << 16);
        if (!(fabsf(v) < 1e8f)) insane++;
    }
    if (insane) atomicAdd(&cnt, insane);
    __syncthreads();
    const bool f32 = (cnt > 8);
    if (tid == 0) ws[FLAG_OFF] = f32 ? 1.0f : 0.0f;
    if (f32) prep_body<true >(W_in,b_in,W_out,b_out,W_ih,W_hh,b_ih,b_hh,ws,tid);
    else     prep_body<false>(W_in,b_in,W_out,b_out,W_ih,W_hh,b_ih,b_hh,ws,tid);
}

// ---- main LSTM body: zero LDS, h recirculates in-register ----
// F32=false (bf16 inputs): LEAN path.  bf16 features/weights are exact or
// near-exact in fp16; all lo-compensation dropped -> 2 MFMAs per tile,
// no Wlo/xlo/flo registers.  Error budget ~3e-4 vs threshold 3.2e-3.
// F32=true: full fp16 hi/lo split (fp32-equivalent accuracy).
template<bool F32>
__device__ __forceinline__ void lstm_body(const void* __restrict__ pm25,
                                          const void* __restrict__ feat,
                                          const float* __restrict__ ws,
                                          void* __restrict__ out)
{
    const int lane = threadIdx.x & 63;
    const int rho  = lane & 15;      // seq within wave / A-row / D-col
    const int q    = lane >> 4;      // k-block / D-row-block / unit-block
    const int wv   = threadIdx.x >> 6;
    const int wseq = (blockIdx.x*4 + wv) * 16;
    const int seq  = wseq + rho;
    const int bb   = seq / CITY_;
    const int city = seq - bb*CITY_;

    // ---- weights -> fp16 A-fragments (once per wave) ----
    v8hf Whi0[8]; v4hf Whi1[8];
    v8hf Wlo0[8]; v4hf Wlo1[8];      // allocated only when F32 (constexpr-dead)
    #pragma unroll
    for (int tt = 0; tt < 8; ++tt) {
        const float* wr = ws + (16*tt + rho)*32 + 8*q;
        #pragma unroll
        for (int j = 0; j < 8; ++j) {
            const float w = wr[j];
            const _Float16 h = (_Float16)w;
            Whi0[tt][j] = h;
            if constexpr (F32) Wlo0[tt][j] = (_Float16)(w - (float)h);
        }
        const float* wf = ws + 4096 + (16*tt + rho)*16 + 4*q;
        #pragma unroll
        for (int j = 0; j < 4; ++j) {
            const float w = wf[j];
            const _Float16 h = (_Float16)w;
            Whi1[tt][j] = h;
            if constexpr (F32) Wlo1[tt][j] = (_Float16)(w - (float)h);
        }
    }
    float wo8[8];
    #pragma unroll
    for (int j = 0; j < 8; ++j) wo8[j] = ws[6528 + 8*q + j]; // wout[unit 8q+j]
    const float bo = ws[6560];
    const long obase = (long)bb*PRED_*CITY_ + city;

    // ---- per-lane direct feature loads (no LDS): elems 4q..4q+3.
    // elem 13 = constant 1.0 (bias column); 14,15 = 0.
    long fbase = ((long)(bb*(HIST_+PRED_) + HIST_)*CITY_ + city)*FEAT_;
    float fn[4];
    auto ldfeat = [&]() {            // prefetch one step's 4 elems into regs
        #pragma unroll
        for (int j = 0; j < 4; ++j) {
            const int e = 4*q + j;
            fn[j] = (e < FEAT_) ? ldin<F32>(feat, fbase + e)
                                : (e == FEAT_ ? 1.0f : 0.0f);
        }
        fbase += CITY_ * FEAT_;
    };
    v4hf fhi, flo;
    auto convf = [&]() {             // fn (step t raw) -> fp16 fragment(s)
        #pragma unroll
        for (int jj = 0; jj < 2; ++jj) {
            const v2hf ph = pkrtz(fn[2*jj], fn[2*jj+1]);
            fhi[2*jj] = ph[0]; fhi[2*jj+1] = ph[1];
            if constexpr (F32) {
                const v2hf pl = pkrtz(fn[2*jj] - (float)ph[0],
                                      fn[2*jj+1] - (float)ph[1]);
                flo[2*jj] = pl[0]; flo[2*jj+1] = pl[1];
            }
        }
    };

    float cst[8];                    // c-state, units 8q+psi, seq rho
    v8hf  xhi, xlo;                  // h: next step's B chunk0 (in-lane!)

    auto finishT = [&](v4f (&acc)[8], int t, auto T0flag) {
        constexpr bool T0 = decltype(T0flag)::value;
        // psi = 4*(tt&1)+r: i=acc[tl], f=acc[2+tl], g=acc[4+tl], o=acc[6+tl]
        float h[8];
        #pragma unroll
        for (int psi = 0; psi < 8; ++psi) {
            const int tl = psi >> 2, r = psi & 3;
            const float I = sigf(acc[tl][r]);
            const float G = tanhf_(acc[4+tl][r]);
            const float O = sigf(acc[6+tl][r]);
            float c;
            if constexpr (T0) c = I*G;
            else              c = fmaf(sigf(acc[2+tl][r]), cst[psi], I*G);
            cst[psi] = c;
            h[psi] = O * tanhf_(c);
        }
        #pragma unroll
        for (int jj = 0; jj < 4; ++jj) {   // pack -> next B fragment
            const v2hf ph = pkrtz(h[2*jj], h[2*jj+1]);
            xhi[2*jj] = ph[0]; xhi[2*jj+1] = ph[1];
            if constexpr (F32) {           // lo exactly compensates RTZ
                const v2hf pl = pkrtz(h[2*jj] - (float)ph[0],
                                      h[2*jj+1] - (float)ph[1]);
                xlo[2*jj] = pl[0]; xlo[2*jj+1] = pl[1];
            }
        }
        float y = 0.0f;                    // y_t = wout . h + bout
        #pragma unroll
        for (int psi = 0; psi < 8; ++psi) y = fmaf(wo8[psi], h[psi], y);
        y += __shfl_xor(y, 16);
        y += __shfl_xor(y, 32);
        if (q == 0) stout<F32>(out, obase + (long)t*CITY_, y + bo);
    };

    // ---- t = 0 : gates = a0*(x0-bo) (C-init) + Wf.[feat;1] (h0 = 0) ----
    // (bg0 = bg2 - a0*bo; bias column supplies bg2, C-init supplies -a0*bo.)
    ldfeat();            // t=0 features
    convf();
    ldfeat();            // t=1 features in flight
    {
        const float x0 = ldin<F32>(pm25, (long)(bb*HIST_ + (HIST_-1))*CITY_ + city);
        const float x0b = x0 - bo;
        v4f acc[8];
        #pragma unroll
        for (int tt = 0; tt < 8; ++tt) {
            const v4f a0 = *(const v4f*)(ws + 6272 + 16*tt + 4*q);
            v4f c;
            #pragma unroll
            for (int r = 0; r < 4; ++r) c[r] = a0[r] * x0b;
            v4f a = mfma_k16(Whi1[tt], fhi, c);
            if constexpr (F32) {
                a = mfma_k16(Wlo1[tt], fhi, a);
                a = mfma_k16(Whi1[tt], flo, a);
            }
            acc[tt] = a;
        }
        finishT(acc, 0, TrueT{});
    }

    // ---- t = 1..23 ----
    const v4f zacc = {0.0f, 0.0f, 0.0f, 0.0f};
    #pragma unroll 1
    for (int t = 1; t < PRED_; ++t) {
        convf();                        // features for t (loaded last iter)
        if (t < PRED_-1) ldfeat();      // prefetch t+1
        v4f acc[8];
        #pragma unroll
        for (int tt = 0; tt < 8; ++tt) {
            v4f a = mfma_k32(Whi0[tt], xhi, zacc);
            if constexpr (F32) {
                a = mfma_k32(Wlo0[tt], xhi, a);
                a = mfma_k32(Whi0[tt], xlo, a);
            }
            a = mfma_k16(Whi1[tt], fhi, a);
            if constexpr (F32) {
                a = mfma_k16(Wlo1[tt], fhi, a);
                a = mfma_k16(Whi1[tt], flo, a);
            }
            acc[tt] = a;
        }
        finishT(acc, t, FalseT{});
    }
}

// bf16 kernel: lean register set (~130) -> cap 170 (3 waves/EU) is spill-safe.
__global__ __launch_bounds__(256, 3) void lstm_bf16(
    const void* __restrict__ pm25, const void* __restrict__ feat,
    const float* __restrict__ ws,  void* __restrict__ out)
{
    if (ws[FLAG_OFF] != 0.0f) return;
    lstm_body<false>(pm25, feat, ws, out);
}

// fp32 kernel: full hi/lo set (~190 regs) -> keep cap 256.
__global__ __launch_bounds__(256, 2) void lstm_f32(
    const void* __restrict__ pm25, const void* __restrict__ feat,
    const float* __restrict__ ws,  void* __restrict__ out)
{
    if (ws[FLAG_OFF] != 1.0f) return;
    lstm_body<true>(pm25, feat, ws, out);
}

extern "C" void kernel_launch(void* const* d_in, const int* in_sizes, int n_in,
                              void* d_out, int out_size, void* d_ws, size_t ws_size,
                              hipStream_t stream) {
    const void* pm25  = d_in[0];
    const void* feat  = d_in[1];
    const void* W_in  = d_in[2];
    const void* b_in  = d_in[3];
    const void* W_out = d_in[4];
    const void* b_out = d_in[5];
    const void* W_ih  = d_in[6];
    const void* W_hh  = d_in[7];
    const void* b_ih  = d_in[8];
    const void* b_hh  = d_in[9];
    float* ws = (float*)d_ws;

    prep_all<<<dim3(1), dim3(128), 0, stream>>>(
        (const unsigned short*)feat, W_in, b_in, W_out, b_out,
        W_ih, W_hh, b_ih, b_hh, ws);

    lstm_bf16<<<dim3(BC_/64), dim3(256), 0, stream>>>(pm25, feat, ws, d_out);
    lstm_f32 <<<dim3(BC_/64), dim3(256), 0, stream>>>(pm25, feat, ws, d_out);
}